// Round 13
// baseline (625.681 us; speedup 1.0000x reference)
//
#include <hip/hip_runtime.h>
#include <cmath>

namespace {
constexpr int TT = 100;
constexpr int B = 512;
constexpr int NIN = 512;
constexpr int NOUT = 512;
constexpr int NEURONS = B * NOUT;  // 262144
constexpr int K3B = 3 * NIN;       // 1536 i8 per A row (3 digit planes)
// Fragment-chunk geometry: chunk = 16 rows x 64 k-bytes = 1024B, lane off = fr*64+fq*16.
// A layout: [rt][p][c][g]*1024  (rt=row/128, p=plane, c=k64 block 0..7, g=row16 group 0..7)
// B layout: [nt][c][g]*1024     (no plane dependence; 256KB per matrix)

constexpr double D_I0 = 1e-3;
constexpr double D_KAPPA = (0.75 + 0.66) / 2.0;
constexpr double D_UT = 25.0e-3;
constexpr float F_I0 = (float)D_I0;
constexpr float F_TAU_AMPA = (float)(2e-3 * D_UT / (D_KAPPA * 20.0 * D_I0));
constexpr float F_TAU_GABA = (float)(2e-3 * D_UT / (D_KAPPA * 5.0 * D_I0));
constexpr float F_TAU_SOMA = (float)(2e-3 * D_UT / (D_KAPPA * 5.0 * D_I0));
constexpr float F_TAU_AHP  = (float)(4e-3 * D_UT / (D_KAPPA * 2.0 * D_I0));
constexpr float F_DPI_TAU  = (float)(5.0 * D_I0);
constexpr float F_RESET    = (float)(1.2 * D_I0);
constexpr float F_VR       = (float)(5.0 * D_I0 + D_I0);
constexpr float F_TH       = (float)(2000.0 * D_I0);
constexpr float F_PFB_TH   = (float)(1000.0 * D_I0);
constexpr float F_ALPHA    = 4.0f;
constexpr float F_AMPA_GAIN = (float)(4.0 * 100.0 * D_I0);
constexpr float F_GABA_GAIN = (float)(4.0 * 100.0 * D_I0);
constexpr float F_AHP_GAIN  = (float)(4.0 * 2.0 * D_I0);
constexpr float F_AHP_JUMP  = (float)(4.0 * D_I0);
constexpr float F_PFB_NORM  = (float)(20.0 * D_I0);
constexpr float F_PFB_GAIN  = (float)(100.0 * D_I0);
constexpr float F_ALPHA_DPI = (float)(4.0 * (5.0 * D_I0));
constexpr float F_DT = 1e-3f;
constexpr float F_INIT_MEM = (float)(1.1 * D_I0);
constexpr float F_INV223 = 1.1920928955078125e-7f;  // 2^-23
constexpr unsigned BIAS_MUL = (1u << 14) + (1u << 22);
}  // namespace

typedef __attribute__((ext_vector_type(4))) int i32x4;

// Chunked WT: byte w[k][n] -> [n>>7][k>>6][(n>>4)&7]*1024 + (n&15)*64 + (k&63).
__global__ __launch_bounds__(256) void build_wt(
    const float* __restrict__ Wa, const float* __restrict__ Wg,
    unsigned char* __restrict__ WTa, unsigned char* __restrict__ WTg) {
  const int t = blockIdx.x * 256 + threadIdx.x;  // 65536 threads
  const float* W = (t >> 15) ? Wg : Wa;
  unsigned char* O = (t >> 15) ? WTg : WTa;
  const int r = t & 32767;
  const int n = r >> 6, k8 = r & 63;
  unsigned char b[8];
#pragma unroll
  for (int j = 0; j < 8; ++j)
    b[j] = (unsigned char)(int)rintf(W[(size_t)(k8 * 8 + j) * 512 + n]);
  const size_t addr = (size_t)(n >> 7) * 65536 + (k8 >> 3) * 8192 +
                      ((n >> 4) & 7) * 1024 + (n & 15) * 64 + (k8 & 7) * 8;
  *(unsigned long long*)(O + addr) = *(unsigned long long*)b;
}

// colsum[z*512+n] = sum_k rint(W_z[k][n]); runs once.
__global__ __launch_bounds__(256) void colsum_w(
    const float* __restrict__ Wa, const float* __restrict__ Wg,
    int* __restrict__ colsum) {
  const int t = blockIdx.x * 256 + threadIdx.x;  // 1024 threads
  const int z = t >> 9, n = t & 511;
  const float* W = z ? Wg : Wa;
  int s = 0;
  for (int k = 0; k < 512; ++k) s += (int)rintf(W[(size_t)k * 512 + n]);
  colsum[t] = s;
}

// split3 v2: one WAVE per 1024-elem chunk; per plane writes one lane-contiguous
// 1KB segment. k = rint(x*2^23); p0=k&127, p1=((k>>7)&255)-128, p2=((k>>15)&255)-128.
__global__ __launch_bounds__(256) void split3(
    const float* __restrict__ XA, const float* __restrict__ XG,
    unsigned char* __restrict__ A4a, unsigned char* __restrict__ A4g, int nwpi) {
  const int wid = (blockIdx.x * 256 + threadIdx.x) >> 6;
  const int l = threadIdx.x & 63;
  const float* X = XA;
  unsigned char* O = A4a;
  int w = wid;
  if (w >= nwpi) { X = XG; O = A4g; w -= nwpi; }
  const int rt = w >> 6, rem = w & 63, c = rem >> 3, g = rem & 7;
  const int rl = l >> 2, q = l & 3;
  const float* src = X + (size_t)(rt * 128 + g * 16 + rl) * 512 + c * 64 + q * 16;
  float a[16];
#pragma unroll
  for (int j = 0; j < 4; ++j) {
    const float4 v = *(const float4*)(src + j * 4);
    a[j * 4 + 0] = v.x; a[j * 4 + 1] = v.y; a[j * 4 + 2] = v.z; a[j * 4 + 3] = v.w;
  }
  unsigned int k[16];
#pragma unroll
  for (int e = 0; e < 16; ++e) k[e] = (unsigned int)rintf(a[e] * 8388608.0f);
  unsigned char* base = O + (size_t)rt * 196608 + c * 8192 + g * 1024 + rl * 64 + q * 16;
  unsigned int u[4];
#pragma unroll
  for (int j = 0; j < 4; ++j)
    u[j] = (k[4 * j] & 127u) | ((k[4 * j + 1] & 127u) << 8) |
           ((k[4 * j + 2] & 127u) << 16) | ((k[4 * j + 3] & 127u) << 24);
  *(uint4*)(base) = make_uint4(u[0], u[1], u[2], u[3]);
#pragma unroll
  for (int j = 0; j < 4; ++j)
    u[j] = (((k[4 * j] >> 7) - 128u) & 255u) | ((((k[4 * j + 1] >> 7) - 128u) & 255u) << 8) |
           ((((k[4 * j + 2] >> 7) - 128u) & 255u) << 16) | ((((k[4 * j + 3] >> 7) - 128u) & 255u) << 24);
  *(uint4*)(base + 65536) = make_uint4(u[0], u[1], u[2], u[3]);
#pragma unroll
  for (int j = 0; j < 4; ++j)
    u[j] = (((k[4 * j] >> 15) - 128u) & 255u) | ((((k[4 * j + 1] >> 15) - 128u) & 255u) << 8) |
           ((((k[4 * j + 2] >> 15) - 128u) & 255u) << 16) | ((((k[4 * j + 3] >> 15) - 128u) & 255u) << 24);
  *(uint4*)(base + 131072) = make_uint4(u[0], u[1], u[2], u[3]);
}

// Exact GEMM v4b: identical to v4 except NO min-waves launch-bound hint —
// R10/R11/R12 all show the hint makes the allocator clamp VGPRs below the
// working set and spill (R12: VGPR=64, +83MB scratch writes). Plain bound
// lets it allocate ~116-140 VGPR spill-free -> 3-4 waves/SIMD with 2 blocks/CU.
// INC = RN((digits @ W Horner) + bias) * 2^-23 — bit-identical to rounds 5-12.
__global__ __launch_bounds__(512) void gemm_i8_v4(
    const unsigned char* __restrict__ A4a, const unsigned char* __restrict__ A4g,
    const unsigned char* __restrict__ WTa, const unsigned char* __restrict__ WTg,
    const int* __restrict__ colsum,
    float* __restrict__ INCa, float* __restrict__ INCg, int nwg) {
  __shared__ __align__(16) unsigned char Bl[65536];
  // m-major chunked bijective XCD swizzle: the 8 (n,z) blocks of an m-panel
  // land on one XCD -> A panel HBM-fetched once, L2-reused x8.
  const int bid = blockIdx.x;
  const int L = (bid & 7) * (nwg >> 3) + (bid >> 3);  // nwg % 8 == 0
  const int m = L >> 3, sub = L & 7;
  const int n = sub & 3, z = sub >> 2;
  const unsigned char* A4 = (z ? A4g : A4a) + (size_t)m * 196608;
  const unsigned char* Bg = (z ? WTg : WTa) + (size_t)n * 65536;
  float* C = z ? INCg : INCa;

  const int tid = threadIdx.x;
  const int lane = tid & 63, wave = tid >> 6;
  const int wr = wave >> 2, wc = wave & 3;  // 2x4 waves: 64-row x 32-col tiles
  const int fr = lane & 15, fq = lane >> 4;
  const int loff = fr * 64 + fq * 16;       // lane offset within a 1KB chunk

  // Stage B once: global chunk layout == LDS layout (linear, coalesced, 64KB).
#pragma unroll
  for (int j = 0; j < 8; ++j) {
    const int idx = j * 512 + tid;  // 4096 x 16B
    *(uint4*)&Bl[idx * 16] = *(const uint4*)(Bg + (size_t)idx * 16);
  }

  const unsigned char* A4w = A4 + wr * 4096 + loff;  // + p*65536 + c*8192 + fm*1024
  const unsigned char* Blp = &Bl[wc * 2048 + loff];  // + c*8192 + fn*1024

  // A ring depth 3 (prologue: iters 0,1 = plane2, c=0,1).
  i32x4 fa[3][4];
#pragma unroll
  for (int f = 0; f < 4; ++f) {
    fa[0][f] = *(const i32x4*)(A4w + 131072 + f * 1024);
    fa[1][f] = *(const i32x4*)(A4w + 131072 + 8192 + f * 1024);
  }
  __syncthreads();  // B staged

  // B ring depth 2 (prologue: iter 0).
  i32x4 fb[2][2];
#pragma unroll
  for (int f = 0; f < 2; ++f)
    fb[0][f] = *(const i32x4*)(Blp + f * 1024);

  i32x4 acc[4][2] = {};
#pragma unroll
  for (int it = 0; it < 24; ++it) {
    if (it < 22) {  // A prefetch, distance 2 (static ring slot)
      const int it2 = it + 2;
      const int aoff = (2 - (it2 >> 3)) * 65536 + (it2 & 7) * 8192;
#pragma unroll
      for (int f = 0; f < 4; ++f)
        fa[it2 % 3][f] = *(const i32x4*)(A4w + aoff + f * 1024);
    }
    if (it < 23) {  // B ds_read, distance 1
      const int boff = ((it + 1) & 7) * 8192;
#pragma unroll
      for (int f = 0; f < 2; ++f)
        fb[(it + 1) & 1][f] = *(const i32x4*)(Blp + boff + f * 1024);
    }
#pragma unroll
    for (int fm = 0; fm < 4; ++fm)
#pragma unroll
      for (int fn = 0; fn < 2; ++fn)
        acc[fm][fn] = __builtin_amdgcn_mfma_i32_16x16x64_i8(
            fa[it % 3][fm], fb[it & 1][fn], acc[fm][fn], 0, 0, 0);
    if (it == 7) {   // plane-2 done: Horner scale 2^8 (mod 2^32, exact)
#pragma unroll
      for (int fm = 0; fm < 4; ++fm)
#pragma unroll
        for (int fn = 0; fn < 2; ++fn) acc[fm][fn] = acc[fm][fn] << 8;
    }
    if (it == 15) {  // plane-1 done: scale 2^7
#pragma unroll
      for (int fm = 0; fm < 4; ++fm)
#pragma unroll
        for (int fn = 0; fn < 2; ++fn) acc[fm][fn] = acc[fm][fn] << 7;
    }
  }

  // Epilogue: bias + convert; per-wave LDS transpose (overlay on Bl after one
  // barrier; same-wave lgkmcnt ordering) -> coalesced 128B-row dwordx4 stores.
  // acc: col = lane&15 (+fn*16), row = fq*4+r (+fm*16)  [m89/m91]
  const int crow0 = m * 128 + wr * 64;
  const int ccol0 = n * 128 + wc * 32;
  unsigned bias[2];
#pragma unroll
  for (int fn = 0; fn < 2; ++fn)
    bias[fn] = BIAS_MUL * (unsigned)colsum[z * 512 + ccol0 + fn * 16 + fr];
  __syncthreads();  // all waves done reading Bl before overlay
  float* scratch = (float*)Bl + wave * (16 * 36);
  const int srow = lane >> 2;        // 0..15
  const int scol = (lane & 3) * 8;   // 0,8,16,24
#pragma unroll
  for (int fm = 0; fm < 4; ++fm) {
#pragma unroll
    for (int fn = 0; fn < 2; ++fn)
#pragma unroll
      for (int r = 0; r < 4; ++r) {
        const unsigned tot = (unsigned)acc[fm][fn][r] + bias[fn];
        scratch[(fq * 4 + r) * 36 + fn * 16 + fr] = (float)tot * F_INV223;
      }
    const float4 r0 = *(const float4*)&scratch[srow * 36 + scol];
    const float4 r1 = *(const float4*)&scratch[srow * 36 + scol + 4];
    float* dst = &C[(size_t)(crow0 + fm * 16 + srow) * NOUT + ccol0 + scol];
    *(float4*)dst = r0;
    *(float4*)(dst + 4) = r1;
  }
}

// One thread per neuron; tc timesteps in registers. Matches JAX step() op-for-op.
__global__ __launch_bounds__(256) void neuron_scan(
    const float* __restrict__ inca, const float* __restrict__ incg,
    float* __restrict__ Sout, float* __restrict__ state, int tc, int first) {
  const int idx = blockIdx.x * 256 + threadIdx.x;
  float mem, ampa, gaba, ahp, refr;
  if (first) {
    mem = F_INIT_MEM; ampa = F_I0; gaba = F_I0; ahp = 0.0f; refr = 0.0f;
  } else {
    mem  = state[idx];
    ampa = state[NEURONS + idx];
    gaba = state[2 * NEURONS + idx];
    ahp  = state[3 * NEURONS + idx];
    refr = state[4 * NEURONS + idx];
  }
  for (int t = 0; t < tc; ++t) {
    const float xa = F_AMPA_GAIN * inca[(size_t)t * NEURONS + idx];
    const float xg = F_GABA_GAIN * incg[(size_t)t * NEURONS + idx];
    const float pfb = F_PFB_GAIN / (1.0f + expf(-(mem - F_PFB_TH) / F_PFB_NORM));
    const float dahp = (-F_AHP_GAIN - ahp) / (F_TAU_AHP * (1.0f + F_AHP_GAIN / ahp));
    const float Iin = fmaxf(ampa - gaba + F_I0, F_I0);
    const float Isum = F_VR + ahp - pfb;
    const float dmem = (F_ALPHA * (Iin - Isum) - Isum * mem / F_DPI_TAU)
                     / (F_TAU_SOMA * (1.0f + F_ALPHA_DPI / mem));
    const float dampa = (F_I0 - ampa) / F_TAU_AMPA;
    ampa = ampa + xa;
    const float dgaba = (F_I0 - gaba) / F_TAU_GABA;
    gaba = gaba + xg;
    refr = refr - (refr > 0.0f ? 1.0f : 0.0f);
    mem = mem + F_DT * dmem * (refr <= 0.0f ? 1.0f : 0.0f);
    ahp = ahp + F_DT * dahp;
    ampa = ampa + F_DT * dampa;
    gaba = gaba + F_DT * dgaba;
    const float S = (mem - F_TH) > 0.0f ? 1.0f : 0.0f;
    refr = refr + floorf(S * 5.0f);
    ahp = ahp + F_AHP_JUMP * S;
    mem = F_RESET * S + mem * (1.0f - S);
    mem = fmaxf(mem, F_I0);
    Sout[(size_t)t * NEURONS + idx] = S;
  }
  state[idx] = mem;
  state[NEURONS + idx] = ampa;
  state[2 * NEURONS + idx] = gaba;
  state[3 * NEURONS + idx] = ahp;
  state[4 * NEURONS + idx] = refr;
}

extern "C" void kernel_launch(void* const* d_in, const int* in_sizes, int n_in,
                              void* d_out, int out_size, void* d_ws, size_t ws_size,
                              hipStream_t stream) {
  const float* XA = (const float*)d_in[0];
  const float* XG = (const float*)d_in[1];
  const float* WA = (const float*)d_in[2];
  const float* WG = (const float*)d_in[3];
  float* S = (float*)d_out;

  // need(tc) = WT(0.5MB)+colsum(4KB)+state(5.25MB) + tc*(A4 1.5MB + INC 2MB)
  int tc = 1;
  const int cands[8] = {100, 50, 25, 20, 10, 5, 2, 1};
  for (int i = 0; i < 8; ++i) {
    const size_t need = 5771264ull + (size_t)cands[i] * 3670016ull;
    if (need <= ws_size) { tc = cands[i]; break; }
  }

  unsigned char* WTa = (unsigned char*)d_ws;
  unsigned char* WTg = WTa + (size_t)NOUT * 512;
  int* colsum = (int*)(WTg + (size_t)NOUT * 512);
  unsigned char* A4a = (unsigned char*)(colsum + 1024);
  unsigned char* A4g = A4a + (size_t)tc * B * K3B;
  float* INCa  = (float*)(A4g + (size_t)tc * B * K3B);
  float* INCg  = INCa + (size_t)tc * NEURONS;
  float* state = INCg + (size_t)tc * NEURONS;

  build_wt<<<256, 256, 0, stream>>>(WA, WG, WTa, WTg);
  colsum_w<<<4, 256, 0, stream>>>(WA, WG, colsum);

  const int nwpi = tc * 256;              // split waves per input
  const int splitBlocks = nwpi / 2;       // 2 inputs, 4 waves/block
  const int nm = tc * B / 128;
  const int nwg = nm * 8;
  const int nch = TT / tc;
  for (int c = 0; c < nch; ++c) {
    const size_t inOff = (size_t)c * tc * B * NIN;
    split3<<<splitBlocks, 256, 0, stream>>>(XA + inOff, XG + inOff, A4a, A4g, nwpi);
    gemm_i8_v4<<<nwg, 512, 0, stream>>>(A4a, A4g, WTa, WTg, colsum, INCa, INCg, nwg);
    neuron_scan<<<NEURONS / 256, 256, 0, stream>>>(
        INCa, INCg, S + (size_t)c * tc * NEURONS, state, tc, c == 0 ? 1 : 0);
  }
}

// Round 14
// 372.320 us; speedup vs baseline: 1.6805x; 1.6805x over previous
//
#include <hip/hip_runtime.h>
#include <cmath>

namespace {
constexpr int TT = 100;
constexpr int B = 512;
constexpr int NIN = 512;
constexpr int NOUT = 512;
constexpr int NEURONS = B * NOUT;  // 262144
constexpr int K3B = 3 * NIN;       // 1536 i8 per A row (3 digit planes)
// Fragment-chunk geometry: chunk = 16 rows x 64 k-bytes = 1024B, lane off = fr*64+fq*16.
// A layout: [rt][p][c][g]*1024  (rt=row/128, p=plane, c=k64 block 0..7, g=row16 group 0..7)
// B layout: [nt][c][g]*1024     (no plane dependence; 256KB per matrix)
// Every BK=128B K-step of a tile is a CONTIGUOUS 16KB segment in these layouts.

constexpr double D_I0 = 1e-3;
constexpr double D_KAPPA = (0.75 + 0.66) / 2.0;
constexpr double D_UT = 25.0e-3;
constexpr float F_I0 = (float)D_I0;
constexpr float F_TAU_AMPA = (float)(2e-3 * D_UT / (D_KAPPA * 20.0 * D_I0));
constexpr float F_TAU_GABA = (float)(2e-3 * D_UT / (D_KAPPA * 5.0 * D_I0));
constexpr float F_TAU_SOMA = (float)(2e-3 * D_UT / (D_KAPPA * 5.0 * D_I0));
constexpr float F_TAU_AHP  = (float)(4e-3 * D_UT / (D_KAPPA * 2.0 * D_I0));
constexpr float F_DPI_TAU  = (float)(5.0 * D_I0);
constexpr float F_RESET    = (float)(1.2 * D_I0);
constexpr float F_VR       = (float)(5.0 * D_I0 + D_I0);
constexpr float F_TH       = (float)(2000.0 * D_I0);
constexpr float F_PFB_TH   = (float)(1000.0 * D_I0);
constexpr float F_ALPHA    = 4.0f;
constexpr float F_AMPA_GAIN = (float)(4.0 * 100.0 * D_I0);
constexpr float F_GABA_GAIN = (float)(4.0 * 100.0 * D_I0);
constexpr float F_AHP_GAIN  = (float)(4.0 * 2.0 * D_I0);
constexpr float F_AHP_JUMP  = (float)(4.0 * D_I0);
constexpr float F_PFB_NORM  = (float)(20.0 * D_I0);
constexpr float F_PFB_GAIN  = (float)(100.0 * D_I0);
constexpr float F_ALPHA_DPI = (float)(4.0 * (5.0 * D_I0));
constexpr float F_DT = 1e-3f;
constexpr float F_INIT_MEM = (float)(1.1 * D_I0);
constexpr float F_INV223 = 1.1920928955078125e-7f;  // 2^-23
constexpr unsigned BIAS_MUL = (1u << 14) + (1u << 22);
}  // namespace

typedef __attribute__((ext_vector_type(4))) int i32x4;

__device__ __forceinline__ void gload_lds16(const void* g, void* l) {
  __builtin_amdgcn_global_load_lds(
      (const __attribute__((address_space(1))) void*)g,
      (__attribute__((address_space(3))) void*)l, 16, 0, 0);
}

// Chunked WT: byte w[k][n] -> [n>>7][k>>6][(n>>4)&7]*1024 + (n&15)*64 + (k&63).
__global__ __launch_bounds__(256) void build_wt(
    const float* __restrict__ Wa, const float* __restrict__ Wg,
    unsigned char* __restrict__ WTa, unsigned char* __restrict__ WTg) {
  const int t = blockIdx.x * 256 + threadIdx.x;  // 65536 threads
  const float* W = (t >> 15) ? Wg : Wa;
  unsigned char* O = (t >> 15) ? WTg : WTa;
  const int r = t & 32767;
  const int n = r >> 6, k8 = r & 63;
  unsigned char b[8];
#pragma unroll
  for (int j = 0; j < 8; ++j)
    b[j] = (unsigned char)(int)rintf(W[(size_t)(k8 * 8 + j) * 512 + n]);
  const size_t addr = (size_t)(n >> 7) * 65536 + (k8 >> 3) * 8192 +
                      ((n >> 4) & 7) * 1024 + (n & 15) * 64 + (k8 & 7) * 8;
  *(unsigned long long*)(O + addr) = *(unsigned long long*)b;
}

// colsum[z*512+n] = sum_k rint(W_z[k][n]); runs once.
__global__ __launch_bounds__(256) void colsum_w(
    const float* __restrict__ Wa, const float* __restrict__ Wg,
    int* __restrict__ colsum) {
  const int t = blockIdx.x * 256 + threadIdx.x;  // 1024 threads
  const int z = t >> 9, n = t & 511;
  const float* W = z ? Wg : Wa;
  int s = 0;
  for (int k = 0; k < 512; ++k) s += (int)rintf(W[(size_t)k * 512 + n]);
  colsum[t] = s;
}

// split3 v2: one WAVE per 1024-elem chunk; per plane writes one lane-contiguous
// 1KB segment. k = rint(x*2^23); p0=k&127, p1=((k>>7)&255)-128, p2=((k>>15)&255)-128.
__global__ __launch_bounds__(256) void split3(
    const float* __restrict__ XA, const float* __restrict__ XG,
    unsigned char* __restrict__ A4a, unsigned char* __restrict__ A4g, int nwpi) {
  const int wid = (blockIdx.x * 256 + threadIdx.x) >> 6;
  const int l = threadIdx.x & 63;
  const float* X = XA;
  unsigned char* O = A4a;
  int w = wid;
  if (w >= nwpi) { X = XG; O = A4g; w -= nwpi; }
  const int rt = w >> 6, rem = w & 63, c = rem >> 3, g = rem & 7;
  const int rl = l >> 2, q = l & 3;
  const float* src = X + (size_t)(rt * 128 + g * 16 + rl) * 512 + c * 64 + q * 16;
  float a[16];
#pragma unroll
  for (int j = 0; j < 4; ++j) {
    const float4 v = *(const float4*)(src + j * 4);
    a[j * 4 + 0] = v.x; a[j * 4 + 1] = v.y; a[j * 4 + 2] = v.z; a[j * 4 + 3] = v.w;
  }
  unsigned int k[16];
#pragma unroll
  for (int e = 0; e < 16; ++e) k[e] = (unsigned int)rintf(a[e] * 8388608.0f);
  unsigned char* base = O + (size_t)rt * 196608 + c * 8192 + g * 1024 + rl * 64 + q * 16;
  unsigned int u[4];
#pragma unroll
  for (int j = 0; j < 4; ++j)
    u[j] = (k[4 * j] & 127u) | ((k[4 * j + 1] & 127u) << 8) |
           ((k[4 * j + 2] & 127u) << 16) | ((k[4 * j + 3] & 127u) << 24);
  *(uint4*)(base) = make_uint4(u[0], u[1], u[2], u[3]);
#pragma unroll
  for (int j = 0; j < 4; ++j)
    u[j] = (((k[4 * j] >> 7) - 128u) & 255u) | ((((k[4 * j + 1] >> 7) - 128u) & 255u) << 8) |
           ((((k[4 * j + 2] >> 7) - 128u) & 255u) << 16) | ((((k[4 * j + 3] >> 7) - 128u) & 255u) << 24);
  *(uint4*)(base + 65536) = make_uint4(u[0], u[1], u[2], u[3]);
#pragma unroll
  for (int j = 0; j < 4; ++j)
    u[j] = (((k[4 * j] >> 15) - 128u) & 255u) | ((((k[4 * j + 1] >> 15) - 128u) & 255u) << 8) |
           ((((k[4 * j + 2] >> 15) - 128u) & 255u) << 16) | ((((k[4 * j + 3] >> 15) - 128u) & 255u) << 24);
  *(uint4*)(base + 131072) = make_uint4(u[0], u[1], u[2], u[3]);
}

// Exact GEMM v5 — m97-structure port: 128x128 tile, 4 waves (64x64 each),
// BK=128B, double-buffered LDS for BOTH A and B, staged via global_load_lds
// (pure linear 16KB copies — chunked layouts make every K-step contiguous),
// 2 barriers per K-step. No register rings: the LDS dbuf IS the pipeline
// (R9-R13 showed hipcc destroys register pipelines; it handles this one, m97).
// INC = RN((digits @ W Horner) + bias) * 2^-23 — bit-identical to rounds 5-13.
__global__ __launch_bounds__(256) void gemm_i8_v5(
    const unsigned char* __restrict__ A4a, const unsigned char* __restrict__ A4g,
    const unsigned char* __restrict__ WTa, const unsigned char* __restrict__ WTg,
    const int* __restrict__ colsum,
    float* __restrict__ INCa, float* __restrict__ INCg, int nwg) {
  __shared__ __align__(16) unsigned char Al[32768];  // 2 x 16KB A dbuf
  __shared__ __align__(16) unsigned char Bl[32768];  // 2 x 16KB B dbuf
  // m-major chunked bijective XCD swizzle: the 8 (n,z) blocks of an m-panel
  // land on one XCD -> A panel HBM-fetched once, L2-reused x8.
  const int bid = blockIdx.x;
  const int L = (bid & 7) * (nwg >> 3) + (bid >> 3);  // nwg % 8 == 0
  const int m = L >> 3, sub = L & 7;
  const int n = sub & 3, z = sub >> 2;
  const unsigned char* A4 = (z ? A4g : A4a) + (size_t)m * 196608;
  const unsigned char* Bg = (z ? WTg : WTa) + (size_t)n * 65536;
  float* C = z ? INCg : INCa;

  const int tid = threadIdx.x;
  const int lane = tid & 63, wave = tid >> 6;
  const int wr = wave >> 1, wc = wave & 1;  // 2x2 waves: 64x64 out each
  const int fr = lane & 15, fq = lane >> 4;
  const int goff = tid * 16;                 // per-lane global offset
  const int woff = wave * 1024;              // wave-uniform LDS base offset

  // Prologue: stage s=0 (plane 2, c-blocks 0,1) into buf 0.
#pragma unroll
  for (int j = 0; j < 4; ++j) {
    gload_lds16(A4 + 131072 + j * 4096 + goff, Al + j * 4096 + woff);
    gload_lds16(Bg + j * 4096 + goff, Bl + j * 4096 + woff);
  }

  i32x4 acc[4][4] = {};
  int buf = 0;
#pragma unroll
  for (int s = 0; s < 12; ++s) {
    __syncthreads();  // stage(s) complete (compiler drains vmcnt before barrier)
    if (s < 11) {     // stage s+1 into the other buffer
      const int s1 = s + 1;
      const int aoff = (2 - (s1 >> 2)) * 65536 + (s1 & 3) * 16384;
      const int boff = (s1 & 3) * 16384;
      const int lb = (buf ^ 1) * 16384 + woff;
#pragma unroll
      for (int j = 0; j < 4; ++j) {
        gload_lds16(A4 + aoff + j * 4096 + goff, Al + lb + j * 4096);
        gload_lds16(Bg + boff + j * 4096 + goff, Bl + lb + j * 4096);
      }
    }
    // Compute current buffer: 2 MFMA-K-steps of 64B each.
#pragma unroll
    for (int ks = 0; ks < 2; ++ks) {
      i32x4 af[4], bf[4];
#pragma unroll
      for (int fm = 0; fm < 4; ++fm)
        af[fm] = *(const i32x4*)&Al[buf * 16384 + ks * 8192 +
                                    (wr * 4 + fm) * 1024 + fr * 64 + fq * 16];
#pragma unroll
      for (int fn = 0; fn < 4; ++fn)
        bf[fn] = *(const i32x4*)&Bl[buf * 16384 + ks * 8192 +
                                    (wc * 4 + fn) * 1024 + fr * 64 + fq * 16];
#pragma unroll
      for (int fm = 0; fm < 4; ++fm)
#pragma unroll
        for (int fn = 0; fn < 4; ++fn)
          acc[fm][fn] = __builtin_amdgcn_mfma_i32_16x16x64_i8(
              af[fm], bf[fn], acc[fm][fn], 0, 0, 0);
    }
    if (s == 3) {   // plane-2 done: Horner scale 2^8 (mod 2^32, exact)
#pragma unroll
      for (int fm = 0; fm < 4; ++fm)
#pragma unroll
        for (int fn = 0; fn < 4; ++fn) acc[fm][fn] = acc[fm][fn] << 8;
    }
    if (s == 7) {   // plane-1 done: scale 2^7
#pragma unroll
      for (int fm = 0; fm < 4; ++fm)
#pragma unroll
        for (int fn = 0; fn < 4; ++fn) acc[fm][fn] = acc[fm][fn] << 7;
    }
    __syncthreads();  // all waves done reading buf before it is restaged
    buf ^= 1;
  }

  // Epilogue (R9-verified): bias + convert; per-wave LDS transpose (overlay on
  // Al, safe after final barrier) -> coalesced 256B-row dwordx4 stores.
  // acc: col = lane&15 (+fn*16), row = fq*4+r (+fm*16)  [m89/m91]
  const int crow0 = m * 128 + wr * 64;
  const int ccol0 = n * 128 + wc * 64;
  unsigned bias[4];
#pragma unroll
  for (int fn = 0; fn < 4; ++fn)
    bias[fn] = BIAS_MUL * (unsigned)colsum[z * 512 + ccol0 + fn * 16 + fr];
  float* scratch = (float*)Al + wave * (16 * 68);
  const int erow = lane >> 4;
  const int ecol = (lane & 15) * 4;
#pragma unroll
  for (int fm = 0; fm < 4; ++fm) {
#pragma unroll
    for (int fn = 0; fn < 4; ++fn)
#pragma unroll
      for (int r = 0; r < 4; ++r) {
        const unsigned tot = (unsigned)acc[fm][fn][r] + bias[fn];
        scratch[(fq * 4 + r) * 68 + fn * 16 + fr] = (float)tot * F_INV223;
      }
    float4 rows[4];
#pragma unroll
    for (int j = 0; j < 4; ++j)
      rows[j] = *(const float4*)&scratch[(erow + 4 * j) * 68 + ecol];
#pragma unroll
    for (int j = 0; j < 4; ++j) {
      const int grow = crow0 + fm * 16 + erow + 4 * j;
      *(float4*)&C[(size_t)grow * NOUT + ccol0 + ecol] = rows[j];
    }
  }
}

// One thread per neuron; tc timesteps in registers. Matches JAX step() op-for-op.
__global__ __launch_bounds__(256) void neuron_scan(
    const float* __restrict__ inca, const float* __restrict__ incg,
    float* __restrict__ Sout, float* __restrict__ state, int tc, int first) {
  const int idx = blockIdx.x * 256 + threadIdx.x;
  float mem, ampa, gaba, ahp, refr;
  if (first) {
    mem = F_INIT_MEM; ampa = F_I0; gaba = F_I0; ahp = 0.0f; refr = 0.0f;
  } else {
    mem  = state[idx];
    ampa = state[NEURONS + idx];
    gaba = state[2 * NEURONS + idx];
    ahp  = state[3 * NEURONS + idx];
    refr = state[4 * NEURONS + idx];
  }
  for (int t = 0; t < tc; ++t) {
    const float xa = F_AMPA_GAIN * inca[(size_t)t * NEURONS + idx];
    const float xg = F_GABA_GAIN * incg[(size_t)t * NEURONS + idx];
    const float pfb = F_PFB_GAIN / (1.0f + expf(-(mem - F_PFB_TH) / F_PFB_NORM));
    const float dahp = (-F_AHP_GAIN - ahp) / (F_TAU_AHP * (1.0f + F_AHP_GAIN / ahp));
    const float Iin = fmaxf(ampa - gaba + F_I0, F_I0);
    const float Isum = F_VR + ahp - pfb;
    const float dmem = (F_ALPHA * (Iin - Isum) - Isum * mem / F_DPI_TAU)
                     / (F_TAU_SOMA * (1.0f + F_ALPHA_DPI / mem));
    const float dampa = (F_I0 - ampa) / F_TAU_AMPA;
    ampa = ampa + xa;
    const float dgaba = (F_I0 - gaba) / F_TAU_GABA;
    gaba = gaba + xg;
    refr = refr - (refr > 0.0f ? 1.0f : 0.0f);
    mem = mem + F_DT * dmem * (refr <= 0.0f ? 1.0f : 0.0f);
    ahp = ahp + F_DT * dahp;
    ampa = ampa + F_DT * dampa;
    gaba = gaba + F_DT * dgaba;
    const float S = (mem - F_TH) > 0.0f ? 1.0f : 0.0f;
    refr = refr + floorf(S * 5.0f);
    ahp = ahp + F_AHP_JUMP * S;
    mem = F_RESET * S + mem * (1.0f - S);
    mem = fmaxf(mem, F_I0);
    Sout[(size_t)t * NEURONS + idx] = S;
  }
  state[idx] = mem;
  state[NEURONS + idx] = ampa;
  state[2 * NEURONS + idx] = gaba;
  state[3 * NEURONS + idx] = ahp;
  state[4 * NEURONS + idx] = refr;
}

extern "C" void kernel_launch(void* const* d_in, const int* in_sizes, int n_in,
                              void* d_out, int out_size, void* d_ws, size_t ws_size,
                              hipStream_t stream) {
  const float* XA = (const float*)d_in[0];
  const float* XG = (const float*)d_in[1];
  const float* WA = (const float*)d_in[2];
  const float* WG = (const float*)d_in[3];
  float* S = (float*)d_out;

  // need(tc) = WT(0.5MB)+colsum(4KB)+state(5.25MB) + tc*(A4 1.5MB + INC 2MB)
  int tc = 1;
  const int cands[8] = {100, 50, 25, 20, 10, 5, 2, 1};
  for (int i = 0; i < 8; ++i) {
    const size_t need = 5771264ull + (size_t)cands[i] * 3670016ull;
    if (need <= ws_size) { tc = cands[i]; break; }
  }

  unsigned char* WTa = (unsigned char*)d_ws;
  unsigned char* WTg = WTa + (size_t)NOUT * 512;
  int* colsum = (int*)(WTg + (size_t)NOUT * 512);
  unsigned char* A4a = (unsigned char*)(colsum + 1024);
  unsigned char* A4g = A4a + (size_t)tc * B * K3B;
  float* INCa  = (float*)(A4g + (size_t)tc * B * K3B);
  float* INCg  = INCa + (size_t)tc * NEURONS;
  float* state = INCg + (size_t)tc * NEURONS;

  build_wt<<<256, 256, 0, stream>>>(WA, WG, WTa, WTg);
  colsum_w<<<4, 256, 0, stream>>>(WA, WG, colsum);

  const int nwpi = tc * 256;              // split waves per input
  const int splitBlocks = nwpi / 2;       // 2 inputs, 4 waves/block
  const int nm = tc * B / 128;
  const int nwg = nm * 8;
  const int nch = TT / tc;
  for (int c = 0; c < nch; ++c) {
    const size_t inOff = (size_t)c * tc * B * NIN;
    split3<<<splitBlocks, 256, 0, stream>>>(XA + inOff, XG + inOff, A4a, A4g, nwpi);
    gemm_i8_v5<<<nwg, 256, 0, stream>>>(A4a, A4g, WTa, WTg, colsum, INCa, INCg, nwg);
    neuron_scan<<<NEURONS / 256, 256, 0, stream>>>(
        INCa, INCg, S + (size_t)c * tc * NEURONS, state, tc, c == 0 ? 1 : 0);
  }
}